// Round 10
// baseline (173.409 us; speedup 1.0000x reference)
//
#include <hip/hip_runtime.h>
#include <hip/hip_bf16.h>

#define D 128
#define NBINS 157    // ceil(10000/64) bins of 64 nodes (dst >> 6)
#define BIN_CAP 5120 // max padded edge total within one bin (mean 4076)
#define EPB 4096     // edges per scatter block (512 thr x 8)
#define SCAP 96      // per-(bin,block) slab capacity (max observed ~56)
#define SLABW (NBINS * SCAP)   // ints per bin across all block slabs

__device__ __forceinline__ unsigned rne_bf16(float f) {
    unsigned u = __float_as_uint(f);
    return (u + 0x7FFFu + ((u >> 16) & 1u)) >> 16;
}
__device__ __forceinline__ float bf16_lo(unsigned u) { return __uint_as_float(u << 16); }
__device__ __forceinline__ float bf16_hi(unsigned u) { return __uint_as_float(u & 0xFFFF0000u); }

// ---------- K1: fused [Y = X@W (unscaled, fp32)] + [bin_scatter to slabs] ----------
__global__ __launch_bounds__(512) void fused_gemm_scatter(
        const float* __restrict__ X, const float* __restrict__ W,
        float* __restrict__ Y,
        const int* __restrict__ src, const int* __restrict__ dst,
        int* __restrict__ cntMat, int* __restrict__ binned,
        int E, int N, int gGemm) {
    __shared__ float smem[D * D];   // 64 KB, dual-purpose
    int tid = threadIdx.x;

    if ((int)blockIdx.x < gGemm) {
        {
            const float4* W4 = (const float4*)W;
            float4* Ws4 = (float4*)smem;
            #pragma unroll
            for (int i = 0; i < 8; ++i)
                Ws4[tid + 512 * i] = W4[tid + 512 * i];
        }
        __syncthreads();
        const float2* Ws2 = (const float2*)smem;
        int col2 = tid & 63;
        int wv   = __builtin_amdgcn_readfirstlane(tid >> 6);   // 0..7
        int row0 = blockIdx.x * 32 + wv * 4;
        if (row0 >= N) return;

        const float4* xr[4];
        #pragma unroll
        for (int r = 0; r < 4; ++r) {
            int rr = row0 + r; if (rr > N - 1) rr = N - 1;
            xr[r] = (const float4*)(X + (size_t)rr * D);
        }
        float accx[4] = {0.f, 0.f, 0.f, 0.f};
        float accy[4] = {0.f, 0.f, 0.f, 0.f};
        #pragma unroll 8
        for (int kb = 0; kb < 32; ++kb) {
            float4 xv[4];
            #pragma unroll
            for (int r = 0; r < 4; ++r) xv[r] = xr[r][kb];
            #pragma unroll
            for (int kk = 0; kk < 4; ++kk) {
                float2 w = Ws2[(4 * kb + kk) * 64 + col2];
                #pragma unroll
                for (int r = 0; r < 4; ++r) {
                    float xs = ((const float*)&xv[r])[kk];
                    accx[r] = fmaf(xs, w.x, accx[r]);
                    accy[r] = fmaf(xs, w.y, accy[r]);
                }
            }
        }
        #pragma unroll
        for (int r = 0; r < 4; ++r) {
            int rr = row0 + r;
            if (rr < N)
                ((float2*)Y)[(size_t)rr * 64 + col2] = make_float2(accx[r], accy[r]);
        }
    } else {
        int* cnt   = (int*)smem;
        int* loff  = cnt + 160;
        int* scur  = cnt + 320;
        int* stage = cnt + 480;      // 4096 ints
        for (int b = tid; b < NBINS; b += 512) cnt[b] = 0;
        __syncthreads();

        int bid = blockIdx.x - gGemm;
        int base = bid * EPB + tid * 8;
        int s[8], dl[8], bn[8];
        int ne = 0;
        if (base + 8 <= E) {
            const int4* s4 = (const int4*)(src + base);
            const int4* d4 = (const int4*)(dst + base);
            int4 a0 = s4[0], a1 = s4[1], c0 = d4[0], c1 = d4[1];
            int ss[8] = {a0.x, a0.y, a0.z, a0.w, a1.x, a1.y, a1.z, a1.w};
            int dd[8] = {c0.x, c0.y, c0.z, c0.w, c1.x, c1.y, c1.z, c1.w};
            ne = 8;
            #pragma unroll
            for (int i = 0; i < 8; ++i) { s[i] = ss[i]; bn[i] = dd[i] >> 6; dl[i] = dd[i] & 63; }
        } else {
            for (int i = 0; i < 8; ++i) {
                int e = base + i;
                if (e < E) { s[ne] = src[e]; int d = dst[e]; bn[ne] = d >> 6; dl[ne] = d & 63; ++ne; }
            }
        }
        for (int i = 0; i < ne; ++i) atomicAdd(&cnt[bn[i]], 1);   // native ds_add (int)
        __syncthreads();

        if (tid < 64) {
            int c0 = (3 * tid     < NBINS) ? cnt[3 * tid    ] : 0;
            int c1 = (3 * tid + 1 < NBINS) ? cnt[3 * tid + 1] : 0;
            int c2 = (3 * tid + 2 < NBINS) ? cnt[3 * tid + 2] : 0;
            int tsum = c0 + c1 + c2;
            int incl = tsum;
            #pragma unroll
            for (int off = 1; off < 64; off <<= 1) {
                int t = __shfl_up(incl, off);
                if (tid >= off) incl += t;
            }
            int excl = incl - tsum;
            if (3 * tid < NBINS)     { loff[3 * tid]     = excl;           scur[3 * tid]     = excl; }
            if (3 * tid + 1 < NBINS) { loff[3 * tid + 1] = excl + c0;      scur[3 * tid + 1] = excl + c0; }
            if (3 * tid + 2 < NBINS) { loff[3 * tid + 2] = excl + c0 + c1; scur[3 * tid + 2] = excl + c0 + c1; }
        }
        __syncthreads();

        for (int i = 0; i < ne; ++i) {
            int p = atomicAdd(&scur[bn[i]], 1);
            stage[p] = s[i] | (dl[i] << 14);      // src | dstLocal<<14
        }
        __syncthreads();

        int wv = tid >> 6, lane = tid & 63;
        for (int b = wv; b < NBINS; b += 8) {
            int n = cnt[b], so = loff[b];
            int* dstp = binned + b * SLABW + bid * SCAP;
            for (int i = lane; i < n; i += 64) dstp[i] = stage[so + i];
            if (lane == 0) cntMat[b * NBINS + bid] = n;
        }
    }
}

// ---------- K2: counting sort @1024 threads, slab input ----------
__global__ __launch_bounds__(1024) void sort_bins(const int* __restrict__ cntMat,
                                                  const int* __restrict__ binned,
                                                  unsigned short* __restrict__ csr16,
                                                  float* __restrict__ dinv,
                                                  int* __restrict__ nodeStart,
                                                  int* __restrict__ nodeEnd,
                                                  const float* __restrict__ Y,
                                                  unsigned* __restrict__ Zb,
                                                  unsigned* __restrict__ Zb2, int N) {
    __shared__ int h[16][64];            // 4 KB
    __shared__ int cur[16][64];          // 4 KB
    __shared__ int scnt[NBINS];          // per-slab counts for this bin
    __shared__ float sdinv[64];
    __shared__ int padTot;
    __shared__ int stage[BIN_CAP];       // 20 KB
    int b = blockIdx.x, tid = threadIdx.x;
    int wv = tid >> 6, lane = tid & 63;
    h[wv][lane] = 0;
    if (tid < NBINS) scnt[tid] = cntMat[b * NBINS + tid];
    __syncthreads();
    // histogram: waves iterate slabs (same slab->wave mapping reused below!)
    const int* binBase = binned + b * SLABW;
    for (int s = wv; s < NBINS; s += 16) {
        int n = scnt[s];
        const int* sp = binBase + s * SCAP;
        for (int i = lane; i < n; i += 64) atomicAdd(&h[wv][sp[i] >> 14], 1);
    }
    __syncthreads();
    if (tid < 64) {
        int hv[16];
        int deg = 0;
        #pragma unroll
        for (int w2 = 0; w2 < 16; ++w2) { hv[w2] = h[w2][tid]; deg += hv[w2]; }
        int pdeg = (deg + 7) & ~7;            // pad to multiple of 8
        int incl = pdeg;
        #pragma unroll
        for (int off = 1; off < 64; off <<= 1) {
            int t = __shfl_up(incl, off);
            if (tid >= off) incl += t;
        }
        int excl = incl - pdeg;
        int run = excl;
        #pragma unroll
        for (int w2 = 0; w2 < 16; ++w2) { cur[w2][tid] = run; run += hv[w2]; }
        float dv = rsqrtf((float)(deg + 1));  // +1 self loop
        sdinv[tid] = dv;
        if (tid == 63) padTot = incl;
        int node = b * 64 + tid;
        if (node < N) {
            dinv[node]      = dv;
            nodeStart[node] = b * BIN_CAP + excl;
            nodeEnd[node]   = b * BIN_CAP + excl + pdeg;
        }
    }
    __syncthreads();
    int cntPad = padTot;
    for (int i = tid; i < cntPad; i += 1024) stage[i] = N;   // sentinel = zero row
    __syncthreads();
    // scatter: SAME slab->wave mapping as histogram (cur[wv] invariant)
    for (int s = wv; s < NBINS; s += 16) {
        int n = scnt[s];
        const int* sp = binBase + s * SCAP;
        for (int i = lane; i < n; i += 64) {
            int p = sp[i];
            int pos = atomicAdd(&cur[wv][p >> 14], 1);
            stage[pos] = p & 0x3FFF;
        }
    }
    // scale + convert: Zb[node] = bf16(Y[node] * dinv)  (rows owned exclusively)
    {
        const float4* Y4 = (const float4*)Y;
        uint2* Zp = (uint2*)Zb;             // 8 B = 4 bf16
        #pragma unroll
        for (int i = 0; i < 2; ++i) {
            int idx = tid + 1024 * i;       // 64 rows x 32 quads = 2048
            int row = idx >> 5, c = idx & 31;
            int node = b * 64 + row;
            if (node < N) {
                float4 v = Y4[(size_t)node * 32 + c];
                float dv = sdinv[row];
                uint2 o;
                o.x = (rne_bf16(v.y * dv) << 16) | rne_bf16(v.x * dv);
                o.y = (rne_bf16(v.w * dv) << 16) | rne_bf16(v.z * dv);
                Zp[(size_t)node * 32 + c] = o;
            }
        }
    }
    // zero sentinel rows N of BOTH gather buffers (rows < N always written)
    if (b == 0 && tid < 64) {
        Zb [(size_t)N * 64 + tid] = 0u;
        Zb2[(size_t)N * 64 + tid] = 0u;
    }
    __syncthreads();
    unsigned short* bw = csr16 + b * BIN_CAP;
    for (int i = tid; i < cntPad; i += 1024) bw[i] = (unsigned short)stage[i];
}

// ---------- aggregation (R7 proven 2-node version) + optional fused layer-2 GEMM ----------
__global__ __launch_bounds__(256) void aggregate(const unsigned* __restrict__ Zb,
                                                 const int* __restrict__ nodeStart,
                                                 const int* __restrict__ nodeEnd,
                                                 const unsigned short* __restrict__ csr16,
                                                 const float* __restrict__ dinv,
                                                 const float* __restrict__ bias,
                                                 float* __restrict__ Out, int N,
                                                 const float* __restrict__ W2,
                                                 unsigned* __restrict__ Zout) {
    __shared__ float rowsLds[8][128];    // 4 KB (used only in fused mode)
    const bool fused = (W2 != nullptr);
    int wv    = __builtin_amdgcn_readfirstlane(threadIdx.x >> 6);
    int nodeA = blockIdx.x * 8 + wv * 2;
    bool active = (nodeA < N);
    if (!fused && !active) return;
    int lane = threadIdx.x & 63;
    int l16  = lane & 15;       // uint4 slot within 256 B row

    if (active) {
        int nodeB = nodeA + 1;
        bool hasB = (nodeB < N);
        int g = lane >> 4;      // 0..3 edge sub-group

        const uint4* Z4 = (const uint4*)Zb;     // row = 16 uint4
        float a0=0.f,a1=0.f,a2=0.f,a3=0.f,a4=0.f,a5=0.f,a6=0.f,a7=0.f;
        float b0=0.f,b1v=0.f,b2v=0.f,b3=0.f,b4v=0.f,b5=0.f,b6=0.f,b7=0.f;

        int eA = nodeStart[nodeA], endA = nodeEnd[nodeA];
        int eB = 0, endB = 0;
        if (hasB) { eB = nodeStart[nodeB]; endB = nodeEnd[nodeB]; }

        while (eA < endA || eB < endB) {
            int remA = endA - eA; int cntA = remA > 64 ? 64 : (remA > 0 ? remA : 0);
            int remB = endB - eB; int cntB = remB > 64 ? 64 : (remB > 0 ? remB : 0);
            int myA = (lane < cntA) ? (int)csr16[eA + lane] : N;   // sentinel pad
            int myB = (lane < cntB) ? (int)csr16[eB + lane] : N;
            int cmax = cntA > cntB ? cntA : cntB;
            int rounds = cmax >> 2;             // cnts are multiples of 8 (or 0)
            #pragma unroll 16
            for (int j = 0; j < rounds; ++j) {
                int idxA = __shfl(myA, j * 4 + g);
                int idxB = __shfl(myB, j * 4 + g);
                uint4 ua = Z4[idxA * 16 + l16];
                uint4 ub = Z4[idxB * 16 + l16];
                a0 += bf16_lo(ua.x); a1 += bf16_hi(ua.x);
                a2 += bf16_lo(ua.y); a3 += bf16_hi(ua.y);
                a4 += bf16_lo(ua.z); a5 += bf16_hi(ua.z);
                a6 += bf16_lo(ua.w); a7 += bf16_hi(ua.w);
                b0  += bf16_lo(ub.x); b1v += bf16_hi(ub.x);
                b2v += bf16_lo(ub.y); b3  += bf16_hi(ub.y);
                b4v += bf16_lo(ub.z); b5  += bf16_hi(ub.z);
                b6  += bf16_lo(ub.w); b7  += bf16_hi(ub.w);
            }
            eA += cntA; eB += cntB;
        }
        // reduce across the 4 edge-groups (lane bits 4..5)
        #pragma unroll
        for (int m = 16; m <= 32; m <<= 1) {
            a0 += __shfl_xor(a0, m); a1 += __shfl_xor(a1, m);
            a2 += __shfl_xor(a2, m); a3 += __shfl_xor(a3, m);
            a4 += __shfl_xor(a4, m); a5 += __shfl_xor(a5, m);
            a6 += __shfl_xor(a6, m); a7 += __shfl_xor(a7, m);
            b0  += __shfl_xor(b0, m);  b1v += __shfl_xor(b1v, m);
            b2v += __shfl_xor(b2v, m); b3  += __shfl_xor(b3, m);
            b4v += __shfl_xor(b4v, m); b5  += __shfl_xor(b5, m);
            b6  += __shfl_xor(b6, m);  b7  += __shfl_xor(b7, m);
        }
        // lanes 0-15 -> node A; lanes 16-31 -> node B
        int half = lane >> 4;
        if (half == 0 || (half == 1 && hasB)) {
            int node = half ? nodeB : nodeA;
            float r0 = half ? b0  : a0, r1 = half ? b1v : a1;
            float r2 = half ? b2v : a2, r3 = half ? b3  : a3;
            float r4 = half ? b4v : a4, r5 = half ? b5  : a5;
            float r6 = half ? b6  : a6, r7 = half ? b7  : a7;
            uint4 su = Z4[node * 16 + l16];
            float dv = dinv[node];
            const float4* bp4 = (const float4*)bias;
            float4 ba = bp4[l16 * 2], bb = bp4[l16 * 2 + 1];
            float4 o0, o1;
            o0.x = (r0 + bf16_lo(su.x)) * dv + ba.x;
            o0.y = (r1 + bf16_hi(su.x)) * dv + ba.y;
            o0.z = (r2 + bf16_lo(su.y)) * dv + ba.z;
            o0.w = (r3 + bf16_hi(su.y)) * dv + ba.w;
            o1.x = (r4 + bf16_lo(su.z)) * dv + bb.x;
            o1.y = (r5 + bf16_hi(su.z)) * dv + bb.y;
            o1.z = (r6 + bf16_lo(su.w)) * dv + bb.z;
            o1.w = (r7 + bf16_hi(su.w)) * dv + bb.w;
            if (fused) {
                float4* rp = (float4*)&rowsLds[wv * 2 + half][0];
                rp[l16 * 2]     = o0;
                rp[l16 * 2 + 1] = o1;
            } else {
                float4* op = (float4*)Out + (size_t)node * 32 + l16 * 2;
                op[0] = o0;
                op[1] = o1;
            }
        }
    }

    if (fused) {
        __syncthreads();
        int tid  = threadIdx.x;
        int colg = (tid & 31) << 2;          // 4 consecutive cols
        int r    = tid >> 5;                 // 0..7
        int node = blockIdx.x * 8 + r;
        const float* xrow = &rowsLds[r][0];
        float ac0 = 0.f, ac1 = 0.f, ac2 = 0.f, ac3 = 0.f;
        #pragma unroll 8
        for (int k = 0; k < 128; ++k) {      // ascending k == reference order
            float xs = xrow[k];
            float4 w4 = *(const float4*)(W2 + (size_t)k * D + colg);
            ac0 = fmaf(xs, w4.x, ac0);
            ac1 = fmaf(xs, w4.y, ac1);
            ac2 = fmaf(xs, w4.z, ac2);
            ac3 = fmaf(xs, w4.w, ac3);
        }
        if (node < N) {
            float dv = dinv[node];
            uint2 o;
            o.x = (rne_bf16(ac1 * dv) << 16) | rne_bf16(ac0 * dv);
            o.y = (rne_bf16(ac3 * dv) << 16) | rne_bf16(ac2 * dv);
            ((uint2*)Zout)[(size_t)node * 32 + (colg >> 2)] = o;
        }
    }
}

extern "C" void kernel_launch(void* const* d_in, const int* in_sizes, int n_in,
                              void* d_out, int out_size, void* d_ws, size_t ws_size,
                              hipStream_t stream) {
    const float* X  = (const float*)d_in[0];
    const int*   ed = (const int*)d_in[1];
    const float* W1 = (const float*)d_in[2];
    const float* b1 = (const float*)d_in[3];
    const float* W2 = (const float*)d_in[4];
    const float* b2 = (const float*)d_in[5];
    float* out = (float*)d_out;

    const int N = in_sizes[0] / D;       // 10000
    const int E = in_sizes[1] / 2;       // 640000
    const int* src = ed;
    const int* dst = ed + E;

    char* w = (char*)d_ws;
    float*    Y        = (float*)w;            w += (size_t)N * D * sizeof(float);
    unsigned* Zb       = (unsigned*)w;         w += (size_t)(N + 1) * 64 * sizeof(unsigned);
    unsigned* Zb2      = (unsigned*)w;         w += (size_t)(N + 1) * 64 * sizeof(unsigned);
    int*      binned   = (int*)w;              w += (size_t)NBINS * SLABW * sizeof(int);
    unsigned short* csr16 = (unsigned short*)w; w += (size_t)NBINS * BIN_CAP * sizeof(unsigned short);
    float*    dinv     = (float*)w;            w += (size_t)N * sizeof(float);
    int*      nodeStart= (int*)w;              w += (size_t)N * sizeof(int);
    int*      nodeEnd  = (int*)w;              w += (size_t)N * sizeof(int);
    int*      cntMat   = (int*)w;              w += (size_t)NBINS * NBINS * sizeof(int);

    int gGemm1 = (N + 31) / 32;                 // 313
    int gScat  = (E + EPB - 1) / EPB;           // 157
    // ===== ATTRIBUTION PROBE: K1 launched 5x (idempotent: no global atomics).
    // T_K1 = (dur_us - 132.1) / 4. Revert to 1x next round.
    for (int rep = 0; rep < 5; ++rep)
        fused_gemm_scatter<<<gGemm1 + gScat, 512, 0, stream>>>(
            X, W1, Y, src, dst, cntMat, binned, E, N, gGemm1);
    sort_bins<<<NBINS, 1024, 0, stream>>>(cntMat, binned, csr16, dinv,
                                          nodeStart, nodeEnd, Y, Zb, Zb2, N);

    int gAgg = (N + 7) / 8;                     // 1250: two nodes per wave
    // layer 1: aggregate + fused layer-2 linear -> Zb2 (bf16, scaled)
    aggregate<<<gAgg, 256, 0, stream>>>(Zb, nodeStart, nodeEnd, csr16, dinv,
                                        b1, out, N, W2, Zb2);
    // layer 2: aggregate -> final output
    aggregate<<<gAgg, 256, 0, stream>>>(Zb2, nodeStart, nodeEnd, csr16, dinv,
                                        b2, out, N, nullptr, nullptr);
}

// Round 11
// 130.384 us; speedup vs baseline: 1.3300x; 1.3300x over previous
//
#include <hip/hip_runtime.h>
#include <hip/hip_bf16.h>

#define D 128
#define NBINS 157    // ceil(10000/64) bins of 64 nodes (dst >> 6)
#define BIN_CAP 5120 // max padded edge total within one bin (mean 4076)
#define EPB 4096     // edges per scatter block (512 thr x 8)
#define SCAP 96      // per-(bin,block) slab capacity (max observed ~56)
#define SLABW (NBINS * SCAP)   // ints per bin across all block slabs

__device__ __forceinline__ unsigned rne_bf16(float f) {
    unsigned u = __float_as_uint(f);
    return (u + 0x7FFFu + ((u >> 16) & 1u)) >> 16;
}
__device__ __forceinline__ float bf16_lo(unsigned u) { return __uint_as_float(u << 16); }
__device__ __forceinline__ float bf16_hi(unsigned u) { return __uint_as_float(u & 0xFFFF0000u); }

// ---------- K1: fused [Y = X@W (unscaled, fp32)] + [bin_scatter to slabs] ----------
__global__ __launch_bounds__(512) void fused_gemm_scatter(
        const float* __restrict__ X, const float* __restrict__ W,
        float* __restrict__ Y,
        const int* __restrict__ src, const int* __restrict__ dst,
        int* __restrict__ cntMat, int* __restrict__ binned,
        int E, int N, int gGemm) {
    __shared__ float smem[D * D];   // 64 KB, dual-purpose
    int tid = threadIdx.x;

    if ((int)blockIdx.x < gGemm) {
        {
            const float4* W4 = (const float4*)W;
            float4* Ws4 = (float4*)smem;
            #pragma unroll
            for (int i = 0; i < 8; ++i)
                Ws4[tid + 512 * i] = W4[tid + 512 * i];
        }
        __syncthreads();
        const float2* Ws2 = (const float2*)smem;
        int col2 = tid & 63;
        int wv   = __builtin_amdgcn_readfirstlane(tid >> 6);   // 0..7
        int row0 = blockIdx.x * 32 + wv * 4;
        if (row0 >= N) return;

        const float4* xr[4];
        #pragma unroll
        for (int r = 0; r < 4; ++r) {
            int rr = row0 + r; if (rr > N - 1) rr = N - 1;
            xr[r] = (const float4*)(X + (size_t)rr * D);
        }
        float accx[4] = {0.f, 0.f, 0.f, 0.f};
        float accy[4] = {0.f, 0.f, 0.f, 0.f};
        #pragma unroll 8
        for (int kb = 0; kb < 32; ++kb) {
            float4 xv[4];
            #pragma unroll
            for (int r = 0; r < 4; ++r) xv[r] = xr[r][kb];
            #pragma unroll
            for (int kk = 0; kk < 4; ++kk) {
                float2 w = Ws2[(4 * kb + kk) * 64 + col2];
                #pragma unroll
                for (int r = 0; r < 4; ++r) {
                    float xs = ((const float*)&xv[r])[kk];
                    accx[r] = fmaf(xs, w.x, accx[r]);
                    accy[r] = fmaf(xs, w.y, accy[r]);
                }
            }
        }
        #pragma unroll
        for (int r = 0; r < 4; ++r) {
            int rr = row0 + r;
            if (rr < N)
                ((float2*)Y)[(size_t)rr * 64 + col2] = make_float2(accx[r], accy[r]);
        }
    } else {
        int* cnt   = (int*)smem;
        int* loff  = cnt + 160;
        int* scur  = cnt + 320;
        int* stage = cnt + 480;      // 4096 ints
        for (int b = tid; b < NBINS; b += 512) cnt[b] = 0;
        __syncthreads();

        int bid = blockIdx.x - gGemm;
        int base = bid * EPB + tid * 8;
        int s[8], dl[8], bn[8];
        int ne = 0;
        if (base + 8 <= E) {
            const int4* s4 = (const int4*)(src + base);
            const int4* d4 = (const int4*)(dst + base);
            int4 a0 = s4[0], a1 = s4[1], c0 = d4[0], c1 = d4[1];
            int ss[8] = {a0.x, a0.y, a0.z, a0.w, a1.x, a1.y, a1.z, a1.w};
            int dd[8] = {c0.x, c0.y, c0.z, c0.w, c1.x, c1.y, c1.z, c1.w};
            ne = 8;
            #pragma unroll
            for (int i = 0; i < 8; ++i) { s[i] = ss[i]; bn[i] = dd[i] >> 6; dl[i] = dd[i] & 63; }
        } else {
            for (int i = 0; i < 8; ++i) {
                int e = base + i;
                if (e < E) { s[ne] = src[e]; int d = dst[e]; bn[ne] = d >> 6; dl[ne] = d & 63; ++ne; }
            }
        }
        for (int i = 0; i < ne; ++i) atomicAdd(&cnt[bn[i]], 1);   // native ds_add (int)
        __syncthreads();

        if (tid < 64) {
            int c0 = (3 * tid     < NBINS) ? cnt[3 * tid    ] : 0;
            int c1 = (3 * tid + 1 < NBINS) ? cnt[3 * tid + 1] : 0;
            int c2 = (3 * tid + 2 < NBINS) ? cnt[3 * tid + 2] : 0;
            int tsum = c0 + c1 + c2;
            int incl = tsum;
            #pragma unroll
            for (int off = 1; off < 64; off <<= 1) {
                int t = __shfl_up(incl, off);
                if (tid >= off) incl += t;
            }
            int excl = incl - tsum;
            if (3 * tid < NBINS)     { loff[3 * tid]     = excl;           scur[3 * tid]     = excl; }
            if (3 * tid + 1 < NBINS) { loff[3 * tid + 1] = excl + c0;      scur[3 * tid + 1] = excl + c0; }
            if (3 * tid + 2 < NBINS) { loff[3 * tid + 2] = excl + c0 + c1; scur[3 * tid + 2] = excl + c0 + c1; }
        }
        __syncthreads();

        for (int i = 0; i < ne; ++i) {
            int p = atomicAdd(&scur[bn[i]], 1);
            stage[p] = s[i] | (dl[i] << 14);      // src | dstLocal<<14
        }
        __syncthreads();

        int wv = tid >> 6, lane = tid & 63;
        for (int b = wv; b < NBINS; b += 8) {
            int n = cnt[b], so = loff[b];
            int* dstp = binned + b * SLABW + bid * SCAP;
            for (int i = lane; i < n; i += 64) dstp[i] = stage[so + i];
            if (lane == 0) cntMat[b * NBINS + bid] = n;
        }
    }
}

// ---------- K2: counting sort @1024 threads, slab input ----------
__global__ __launch_bounds__(1024) void sort_bins(const int* __restrict__ cntMat,
                                                  const int* __restrict__ binned,
                                                  unsigned short* __restrict__ csr16,
                                                  float* __restrict__ dinv,
                                                  int* __restrict__ nodeStart,
                                                  int* __restrict__ nodeEnd,
                                                  const float* __restrict__ Y,
                                                  unsigned* __restrict__ Zb,
                                                  unsigned* __restrict__ Zb2, int N) {
    __shared__ int h[16][64];            // 4 KB
    __shared__ int cur[16][64];          // 4 KB
    __shared__ int scnt[NBINS];          // per-slab counts for this bin
    __shared__ float sdinv[64];
    __shared__ int padTot;
    __shared__ int stage[BIN_CAP];       // 20 KB
    int b = blockIdx.x, tid = threadIdx.x;
    int wv = tid >> 6, lane = tid & 63;
    h[wv][lane] = 0;
    if (tid < NBINS) scnt[tid] = cntMat[b * NBINS + tid];
    __syncthreads();
    // histogram: waves iterate slabs (same slab->wave mapping reused below!)
    const int* binBase = binned + b * SLABW;
    for (int s = wv; s < NBINS; s += 16) {
        int n = scnt[s];
        const int* sp = binBase + s * SCAP;
        for (int i = lane; i < n; i += 64) atomicAdd(&h[wv][sp[i] >> 14], 1);
    }
    __syncthreads();
    if (tid < 64) {
        int hv[16];
        int deg = 0;
        #pragma unroll
        for (int w2 = 0; w2 < 16; ++w2) { hv[w2] = h[w2][tid]; deg += hv[w2]; }
        int pdeg = (deg + 7) & ~7;            // pad to multiple of 8
        int incl = pdeg;
        #pragma unroll
        for (int off = 1; off < 64; off <<= 1) {
            int t = __shfl_up(incl, off);
            if (tid >= off) incl += t;
        }
        int excl = incl - pdeg;
        int run = excl;
        #pragma unroll
        for (int w2 = 0; w2 < 16; ++w2) { cur[w2][tid] = run; run += hv[w2]; }
        float dv = rsqrtf((float)(deg + 1));  // +1 self loop
        sdinv[tid] = dv;
        if (tid == 63) padTot = incl;
        int node = b * 64 + tid;
        if (node < N) {
            dinv[node]      = dv;
            nodeStart[node] = b * BIN_CAP + excl;
            nodeEnd[node]   = b * BIN_CAP + excl + pdeg;
        }
    }
    __syncthreads();
    int cntPad = padTot;
    for (int i = tid; i < cntPad; i += 1024) stage[i] = N;   // sentinel = zero row
    __syncthreads();
    // scatter: SAME slab->wave mapping as histogram (cur[wv] invariant)
    for (int s = wv; s < NBINS; s += 16) {
        int n = scnt[s];
        const int* sp = binBase + s * SCAP;
        for (int i = lane; i < n; i += 64) {
            int p = sp[i];
            int pos = atomicAdd(&cur[wv][p >> 14], 1);
            stage[pos] = p & 0x3FFF;
        }
    }
    // scale + convert: Zb[node] = bf16(Y[node] * dinv)  (rows owned exclusively)
    {
        const float4* Y4 = (const float4*)Y;
        uint2* Zp = (uint2*)Zb;             // 8 B = 4 bf16
        #pragma unroll
        for (int i = 0; i < 2; ++i) {
            int idx = tid + 1024 * i;       // 64 rows x 32 quads = 2048
            int row = idx >> 5, c = idx & 31;
            int node = b * 64 + row;
            if (node < N) {
                float4 v = Y4[(size_t)node * 32 + c];
                float dv = sdinv[row];
                uint2 o;
                o.x = (rne_bf16(v.y * dv) << 16) | rne_bf16(v.x * dv);
                o.y = (rne_bf16(v.w * dv) << 16) | rne_bf16(v.z * dv);
                Zp[(size_t)node * 32 + c] = o;
            }
        }
    }
    // zero sentinel rows N of BOTH gather buffers (rows < N always written)
    if (b == 0 && tid < 64) {
        Zb [(size_t)N * 64 + tid] = 0u;
        Zb2[(size_t)N * 64 + tid] = 0u;
    }
    __syncthreads();
    unsigned short* bw = csr16 + b * BIN_CAP;
    for (int i = tid; i < cntPad; i += 1024) bw[i] = (unsigned short)stage[i];
}

// ---------- aggregation: 2-node waves + paired-round loads (guaranteed MLP>=4) ----------
// R8 evidence: 1-stream variant got VGPR=20 (no pipelining). Here each pair of
// rounds issues ALL FOUR row-loads (A0,B0,A1,B1) before any accumulation, so
// >=4 loads are in flight regardless of scheduler choices. Accumulation order
// per node is UNCHANGED (round j rows then round j+1 rows) -> bit-identical.
// rounds is always even (padded deg is a multiple of 8).
__global__ __launch_bounds__(256) void aggregate(const unsigned* __restrict__ Zb,
                                                 const int* __restrict__ nodeStart,
                                                 const int* __restrict__ nodeEnd,
                                                 const unsigned short* __restrict__ csr16,
                                                 const float* __restrict__ dinv,
                                                 const float* __restrict__ bias,
                                                 float* __restrict__ Out, int N,
                                                 const float* __restrict__ W2,
                                                 unsigned* __restrict__ Zout) {
    __shared__ float rowsLds[8][128];    // 4 KB (used only in fused mode)
    const bool fused = (W2 != nullptr);
    int wv    = __builtin_amdgcn_readfirstlane(threadIdx.x >> 6);
    int nodeA = blockIdx.x * 8 + wv * 2;
    bool active = (nodeA < N);
    if (!fused && !active) return;
    int lane = threadIdx.x & 63;
    int l16  = lane & 15;       // uint4 slot within 256 B row

    if (active) {
        int nodeB = nodeA + 1;
        bool hasB = (nodeB < N);
        int g = lane >> 4;      // 0..3 edge sub-group

        const uint4* Z4 = (const uint4*)Zb;     // row = 16 uint4
        float a0=0.f,a1=0.f,a2=0.f,a3=0.f,a4=0.f,a5=0.f,a6=0.f,a7=0.f;
        float b0=0.f,b1v=0.f,b2v=0.f,b3=0.f,b4v=0.f,b5=0.f,b6=0.f,b7=0.f;

        int eA = nodeStart[nodeA], endA = nodeEnd[nodeA];
        int eB = 0, endB = 0;
        if (hasB) { eB = nodeStart[nodeB]; endB = nodeEnd[nodeB]; }

        while (eA < endA || eB < endB) {
            int remA = endA - eA; int cntA = remA > 64 ? 64 : (remA > 0 ? remA : 0);
            int remB = endB - eB; int cntB = remB > 64 ? 64 : (remB > 0 ? remB : 0);
            int myA = (lane < cntA) ? (int)csr16[eA + lane] : N;   // sentinel pad
            int myB = (lane < cntB) ? (int)csr16[eB + lane] : N;
            int cmax = cntA > cntB ? cntA : cntB;
            int rounds = cmax >> 2;             // multiple of 2 (cnts multiple of 8)
            #pragma unroll 8
            for (int j = 0; j < rounds; j += 2) {
                int iA0 = __shfl(myA, j * 4 + g);
                int iB0 = __shfl(myB, j * 4 + g);
                int iA1 = __shfl(myA, j * 4 + 4 + g);
                int iB1 = __shfl(myB, j * 4 + 4 + g);
                uint4 ua0 = Z4[iA0 * 16 + l16];
                uint4 ub0 = Z4[iB0 * 16 + l16];
                uint4 ua1 = Z4[iA1 * 16 + l16];
                uint4 ub1 = Z4[iB1 * 16 + l16];
                // round j (identical order to original)
                a0 += bf16_lo(ua0.x); a1 += bf16_hi(ua0.x);
                a2 += bf16_lo(ua0.y); a3 += bf16_hi(ua0.y);
                a4 += bf16_lo(ua0.z); a5 += bf16_hi(ua0.z);
                a6 += bf16_lo(ua0.w); a7 += bf16_hi(ua0.w);
                b0  += bf16_lo(ub0.x); b1v += bf16_hi(ub0.x);
                b2v += bf16_lo(ub0.y); b3  += bf16_hi(ub0.y);
                b4v += bf16_lo(ub0.z); b5  += bf16_hi(ub0.z);
                b6  += bf16_lo(ub0.w); b7  += bf16_hi(ub0.w);
                // round j+1
                a0 += bf16_lo(ua1.x); a1 += bf16_hi(ua1.x);
                a2 += bf16_lo(ua1.y); a3 += bf16_hi(ua1.y);
                a4 += bf16_lo(ua1.z); a5 += bf16_hi(ua1.z);
                a6 += bf16_lo(ua1.w); a7 += bf16_hi(ua1.w);
                b0  += bf16_lo(ub1.x); b1v += bf16_hi(ub1.x);
                b2v += bf16_lo(ub1.y); b3  += bf16_hi(ub1.y);
                b4v += bf16_lo(ub1.z); b5  += bf16_hi(ub1.z);
                b6  += bf16_lo(ub1.w); b7  += bf16_hi(ub1.w);
            }
            eA += cntA; eB += cntB;
        }
        // reduce across the 4 edge-groups (lane bits 4..5)
        #pragma unroll
        for (int m = 16; m <= 32; m <<= 1) {
            a0 += __shfl_xor(a0, m); a1 += __shfl_xor(a1, m);
            a2 += __shfl_xor(a2, m); a3 += __shfl_xor(a3, m);
            a4 += __shfl_xor(a4, m); a5 += __shfl_xor(a5, m);
            a6 += __shfl_xor(a6, m); a7 += __shfl_xor(a7, m);
            b0  += __shfl_xor(b0, m);  b1v += __shfl_xor(b1v, m);
            b2v += __shfl_xor(b2v, m); b3  += __shfl_xor(b3, m);
            b4v += __shfl_xor(b4v, m); b5  += __shfl_xor(b5, m);
            b6  += __shfl_xor(b6, m);  b7  += __shfl_xor(b7, m);
        }
        // lanes 0-15 -> node A; lanes 16-31 -> node B
        int half = lane >> 4;
        if (half == 0 || (half == 1 && hasB)) {
            int node = half ? nodeB : nodeA;
            float r0 = half ? b0  : a0, r1 = half ? b1v : a1;
            float r2 = half ? b2v : a2, r3 = half ? b3  : a3;
            float r4 = half ? b4v : a4, r5 = half ? b5  : a5;
            float r6 = half ? b6  : a6, r7 = half ? b7  : a7;
            uint4 su = Z4[node * 16 + l16];
            float dv = dinv[node];
            const float4* bp4 = (const float4*)bias;
            float4 ba = bp4[l16 * 2], bb = bp4[l16 * 2 + 1];
            float4 o0, o1;
            o0.x = (r0 + bf16_lo(su.x)) * dv + ba.x;
            o0.y = (r1 + bf16_hi(su.x)) * dv + ba.y;
            o0.z = (r2 + bf16_lo(su.y)) * dv + ba.z;
            o0.w = (r3 + bf16_hi(su.y)) * dv + ba.w;
            o1.x = (r4 + bf16_lo(su.z)) * dv + bb.x;
            o1.y = (r5 + bf16_hi(su.z)) * dv + bb.y;
            o1.z = (r6 + bf16_lo(su.w)) * dv + bb.z;
            o1.w = (r7 + bf16_hi(su.w)) * dv + bb.w;
            if (fused) {
                float4* rp = (float4*)&rowsLds[wv * 2 + half][0];
                rp[l16 * 2]     = o0;
                rp[l16 * 2 + 1] = o1;
            } else {
                float4* op = (float4*)Out + (size_t)node * 32 + l16 * 2;
                op[0] = o0;
                op[1] = o1;
            }
        }
    }

    if (fused) {
        __syncthreads();
        int tid  = threadIdx.x;
        int colg = (tid & 31) << 2;          // 4 consecutive cols
        int r    = tid >> 5;                 // 0..7
        int node = blockIdx.x * 8 + r;
        const float* xrow = &rowsLds[r][0];
        float ac0 = 0.f, ac1 = 0.f, ac2 = 0.f, ac3 = 0.f;
        #pragma unroll 8
        for (int k = 0; k < 128; ++k) {      // ascending k == reference order
            float xs = xrow[k];
            float4 w4 = *(const float4*)(W2 + (size_t)k * D + colg);
            ac0 = fmaf(xs, w4.x, ac0);
            ac1 = fmaf(xs, w4.y, ac1);
            ac2 = fmaf(xs, w4.z, ac2);
            ac3 = fmaf(xs, w4.w, ac3);
        }
        if (node < N) {
            float dv = dinv[node];
            uint2 o;
            o.x = (rne_bf16(ac1 * dv) << 16) | rne_bf16(ac0 * dv);
            o.y = (rne_bf16(ac3 * dv) << 16) | rne_bf16(ac2 * dv);
            ((uint2*)Zout)[(size_t)node * 32 + (colg >> 2)] = o;
        }
    }
}

extern "C" void kernel_launch(void* const* d_in, const int* in_sizes, int n_in,
                              void* d_out, int out_size, void* d_ws, size_t ws_size,
                              hipStream_t stream) {
    const float* X  = (const float*)d_in[0];
    const int*   ed = (const int*)d_in[1];
    const float* W1 = (const float*)d_in[2];
    const float* b1 = (const float*)d_in[3];
    const float* W2 = (const float*)d_in[4];
    const float* b2 = (const float*)d_in[5];
    float* out = (float*)d_out;

    const int N = in_sizes[0] / D;       // 10000
    const int E = in_sizes[1] / 2;       // 640000
    const int* src = ed;
    const int* dst = ed + E;

    char* w = (char*)d_ws;
    float*    Y        = (float*)w;            w += (size_t)N * D * sizeof(float);
    unsigned* Zb       = (unsigned*)w;         w += (size_t)(N + 1) * 64 * sizeof(unsigned);
    unsigned* Zb2      = (unsigned*)w;         w += (size_t)(N + 1) * 64 * sizeof(unsigned);
    int*      binned   = (int*)w;              w += (size_t)NBINS * SLABW * sizeof(int);
    unsigned short* csr16 = (unsigned short*)w; w += (size_t)NBINS * BIN_CAP * sizeof(unsigned short);
    float*    dinv     = (float*)w;            w += (size_t)N * sizeof(float);
    int*      nodeStart= (int*)w;              w += (size_t)N * sizeof(int);
    int*      nodeEnd  = (int*)w;              w += (size_t)N * sizeof(int);
    int*      cntMat   = (int*)w;              w += (size_t)NBINS * NBINS * sizeof(int);

    int gGemm1 = (N + 31) / 32;                 // 313
    int gScat  = (E + EPB - 1) / EPB;           // 157
    fused_gemm_scatter<<<gGemm1 + gScat, 512, 0, stream>>>(
        X, W1, Y, src, dst, cntMat, binned, E, N, gGemm1);
    sort_bins<<<NBINS, 1024, 0, stream>>>(cntMat, binned, csr16, dinv,
                                          nodeStart, nodeEnd, Y, Zb, Zb2, N);

    int gAgg = (N + 7) / 8;                     // 1250: two nodes per wave
    // layer 1: aggregate + fused layer-2 linear -> Zb2 (bf16, scaled)
    aggregate<<<gAgg, 256, 0, stream>>>(Zb, nodeStart, nodeEnd, csr16, dinv,
                                        b1, out, N, W2, Zb2);
    // layer 2: aggregate -> final output
    aggregate<<<gAgg, 256, 0, stream>>>(Zb2, nodeStart, nodeEnd, csr16, dinv,
                                        b2, out, N, nullptr, nullptr);
}

// Round 12
// 130.016 us; speedup vs baseline: 1.3337x; 1.0028x over previous
//
#include <hip/hip_runtime.h>
#include <hip/hip_bf16.h>

#define D 128
#define NBINS 157    // ceil(10000/64) bins of 64 nodes (dst >> 6)
#define BIN_CAP 5120 // max padded edge total within one bin (mean 4076)
#define EPB 4096     // edges per scatter block (512 thr x 8)
#define SCAP 96      // per-(bin,block) slab capacity (max observed ~56)
#define SLABW (NBINS * SCAP)   // ints per bin across all block slabs

__device__ __forceinline__ unsigned rne_bf16(float f) {
    unsigned u = __float_as_uint(f);
    return (u + 0x7FFFu + ((u >> 16) & 1u)) >> 16;
}
__device__ __forceinline__ float bf16_lo(unsigned u) { return __uint_as_float(u << 16); }
__device__ __forceinline__ float bf16_hi(unsigned u) { return __uint_as_float(u & 0xFFFF0000u); }

// ---------- K1: fused [Y = X@W (unscaled, fp32)] + [bin_scatter to slabs] ----------
__global__ __launch_bounds__(512) void fused_gemm_scatter(
        const float* __restrict__ X, const float* __restrict__ W,
        float* __restrict__ Y,
        const int* __restrict__ src, const int* __restrict__ dst,
        int* __restrict__ cntMat, int* __restrict__ binned,
        int E, int N, int gGemm) {
    __shared__ float smem[D * D];   // 64 KB, dual-purpose
    int tid = threadIdx.x;

    if ((int)blockIdx.x < gGemm) {
        {
            const float4* W4 = (const float4*)W;
            float4* Ws4 = (float4*)smem;
            #pragma unroll
            for (int i = 0; i < 8; ++i)
                Ws4[tid + 512 * i] = W4[tid + 512 * i];
        }
        __syncthreads();
        const float2* Ws2 = (const float2*)smem;
        int col2 = tid & 63;
        int wv   = __builtin_amdgcn_readfirstlane(tid >> 6);   // 0..7
        int row0 = blockIdx.x * 32 + wv * 4;
        if (row0 >= N) return;

        const float4* xr[4];
        #pragma unroll
        for (int r = 0; r < 4; ++r) {
            int rr = row0 + r; if (rr > N - 1) rr = N - 1;
            xr[r] = (const float4*)(X + (size_t)rr * D);
        }
        float accx[4] = {0.f, 0.f, 0.f, 0.f};
        float accy[4] = {0.f, 0.f, 0.f, 0.f};
        #pragma unroll 8
        for (int kb = 0; kb < 32; ++kb) {
            float4 xv[4];
            #pragma unroll
            for (int r = 0; r < 4; ++r) xv[r] = xr[r][kb];
            #pragma unroll
            for (int kk = 0; kk < 4; ++kk) {
                float2 w = Ws2[(4 * kb + kk) * 64 + col2];
                #pragma unroll
                for (int r = 0; r < 4; ++r) {
                    float xs = ((const float*)&xv[r])[kk];
                    accx[r] = fmaf(xs, w.x, accx[r]);
                    accy[r] = fmaf(xs, w.y, accy[r]);
                }
            }
        }
        #pragma unroll
        for (int r = 0; r < 4; ++r) {
            int rr = row0 + r;
            if (rr < N)
                ((float2*)Y)[(size_t)rr * 64 + col2] = make_float2(accx[r], accy[r]);
        }
    } else {
        int* cnt   = (int*)smem;
        int* loff  = cnt + 160;
        int* scur  = cnt + 320;
        int* stage = cnt + 480;      // 4096 ints
        for (int b = tid; b < NBINS; b += 512) cnt[b] = 0;
        __syncthreads();

        int bid = blockIdx.x - gGemm;
        int base = bid * EPB + tid * 8;
        int s[8], dl[8], bn[8];
        int ne = 0;
        if (base + 8 <= E) {
            const int4* s4 = (const int4*)(src + base);
            const int4* d4 = (const int4*)(dst + base);
            int4 a0 = s4[0], a1 = s4[1], c0 = d4[0], c1 = d4[1];
            int ss[8] = {a0.x, a0.y, a0.z, a0.w, a1.x, a1.y, a1.z, a1.w};
            int dd[8] = {c0.x, c0.y, c0.z, c0.w, c1.x, c1.y, c1.z, c1.w};
            ne = 8;
            #pragma unroll
            for (int i = 0; i < 8; ++i) { s[i] = ss[i]; bn[i] = dd[i] >> 6; dl[i] = dd[i] & 63; }
        } else {
            for (int i = 0; i < 8; ++i) {
                int e = base + i;
                if (e < E) { s[ne] = src[e]; int d = dst[e]; bn[ne] = d >> 6; dl[ne] = d & 63; ++ne; }
            }
        }
        for (int i = 0; i < ne; ++i) atomicAdd(&cnt[bn[i]], 1);   // native ds_add (int)
        __syncthreads();

        if (tid < 64) {
            int c0 = (3 * tid     < NBINS) ? cnt[3 * tid    ] : 0;
            int c1 = (3 * tid + 1 < NBINS) ? cnt[3 * tid + 1] : 0;
            int c2 = (3 * tid + 2 < NBINS) ? cnt[3 * tid + 2] : 0;
            int tsum = c0 + c1 + c2;
            int incl = tsum;
            #pragma unroll
            for (int off = 1; off < 64; off <<= 1) {
                int t = __shfl_up(incl, off);
                if (tid >= off) incl += t;
            }
            int excl = incl - tsum;
            if (3 * tid < NBINS)     { loff[3 * tid]     = excl;           scur[3 * tid]     = excl; }
            if (3 * tid + 1 < NBINS) { loff[3 * tid + 1] = excl + c0;      scur[3 * tid + 1] = excl + c0; }
            if (3 * tid + 2 < NBINS) { loff[3 * tid + 2] = excl + c0 + c1; scur[3 * tid + 2] = excl + c0 + c1; }
        }
        __syncthreads();

        for (int i = 0; i < ne; ++i) {
            int p = atomicAdd(&scur[bn[i]], 1);
            stage[p] = s[i] | (dl[i] << 14);      // src | dstLocal<<14
        }
        __syncthreads();

        int wv = tid >> 6, lane = tid & 63;
        for (int b = wv; b < NBINS; b += 8) {
            int n = cnt[b], so = loff[b];
            int* dstp = binned + b * SLABW + bid * SCAP;
            for (int i = lane; i < n; i += 64) dstp[i] = stage[so + i];
            if (lane == 0) cntMat[b * NBINS + bid] = n;
        }
    }
}

// ---------- K2: counting sort @1024 threads, slab input ----------
__global__ __launch_bounds__(1024) void sort_bins(const int* __restrict__ cntMat,
                                                  const int* __restrict__ binned,
                                                  unsigned short* __restrict__ csr16,
                                                  float* __restrict__ dinv,
                                                  int* __restrict__ nodeStart,
                                                  int* __restrict__ nodeEnd,
                                                  const float* __restrict__ Y,
                                                  unsigned* __restrict__ Zb,
                                                  unsigned* __restrict__ Zb2, int N) {
    __shared__ int h[16][64];            // 4 KB
    __shared__ int cur[16][64];          // 4 KB
    __shared__ int scnt[NBINS];          // per-slab counts for this bin
    __shared__ float sdinv[64];
    __shared__ int padTot;
    __shared__ int stage[BIN_CAP];       // 20 KB
    int b = blockIdx.x, tid = threadIdx.x;
    int wv = tid >> 6, lane = tid & 63;
    h[wv][lane] = 0;
    if (tid < NBINS) scnt[tid] = cntMat[b * NBINS + tid];
    __syncthreads();
    // histogram: waves iterate slabs (same slab->wave mapping reused below!)
    const int* binBase = binned + b * SLABW;
    for (int s = wv; s < NBINS; s += 16) {
        int n = scnt[s];
        const int* sp = binBase + s * SCAP;
        for (int i = lane; i < n; i += 64) atomicAdd(&h[wv][sp[i] >> 14], 1);
    }
    __syncthreads();
    if (tid < 64) {
        int hv[16];
        int deg = 0;
        #pragma unroll
        for (int w2 = 0; w2 < 16; ++w2) { hv[w2] = h[w2][tid]; deg += hv[w2]; }
        int pdeg = (deg + 7) & ~7;            // pad to multiple of 8
        int incl = pdeg;
        #pragma unroll
        for (int off = 1; off < 64; off <<= 1) {
            int t = __shfl_up(incl, off);
            if (tid >= off) incl += t;
        }
        int excl = incl - pdeg;
        int run = excl;
        #pragma unroll
        for (int w2 = 0; w2 < 16; ++w2) { cur[w2][tid] = run; run += hv[w2]; }
        float dv = rsqrtf((float)(deg + 1));  // +1 self loop
        sdinv[tid] = dv;
        if (tid == 63) padTot = incl;
        int node = b * 64 + tid;
        if (node < N) {
            dinv[node]      = dv;
            nodeStart[node] = b * BIN_CAP + excl;
            nodeEnd[node]   = b * BIN_CAP + excl + pdeg;
        }
    }
    __syncthreads();
    int cntPad = padTot;
    for (int i = tid; i < cntPad; i += 1024) stage[i] = N;   // sentinel = zero row
    __syncthreads();
    // scatter: SAME slab->wave mapping as histogram (cur[wv] invariant)
    for (int s = wv; s < NBINS; s += 16) {
        int n = scnt[s];
        const int* sp = binBase + s * SCAP;
        for (int i = lane; i < n; i += 64) {
            int p = sp[i];
            int pos = atomicAdd(&cur[wv][p >> 14], 1);
            stage[pos] = p & 0x3FFF;
        }
    }
    // scale + convert: Zb[node] = bf16(Y[node] * dinv)  (rows owned exclusively)
    {
        const float4* Y4 = (const float4*)Y;
        uint2* Zp = (uint2*)Zb;             // 8 B = 4 bf16
        #pragma unroll
        for (int i = 0; i < 2; ++i) {
            int idx = tid + 1024 * i;       // 64 rows x 32 quads = 2048
            int row = idx >> 5, c = idx & 31;
            int node = b * 64 + row;
            if (node < N) {
                float4 v = Y4[(size_t)node * 32 + c];
                float dv = sdinv[row];
                uint2 o;
                o.x = (rne_bf16(v.y * dv) << 16) | rne_bf16(v.x * dv);
                o.y = (rne_bf16(v.w * dv) << 16) | rne_bf16(v.z * dv);
                Zp[(size_t)node * 32 + c] = o;
            }
        }
    }
    // zero sentinel rows N of BOTH gather buffers (rows < N always written)
    if (b == 0 && tid < 64) {
        Zb [(size_t)N * 64 + tid] = 0u;
        Zb2[(size_t)N * 64 + tid] = 0u;
    }
    __syncthreads();
    unsigned short* bw = csr16 + b * BIN_CAP;
    for (int i = tid; i < cntPad; i += 1024) bw[i] = (unsigned short)stage[i];
}

// accumulate one round's A/B rows (order matches the original scalar loop)
#define ACC_AB(ua, ub)                                    \
    a0 += bf16_lo(ua.x); a1 += bf16_hi(ua.x);             \
    a2 += bf16_lo(ua.y); a3 += bf16_hi(ua.y);             \
    a4 += bf16_lo(ua.z); a5 += bf16_hi(ua.z);             \
    a6 += bf16_lo(ua.w); a7 += bf16_hi(ua.w);             \
    b0  += bf16_lo(ub.x); b1v += bf16_hi(ub.x);           \
    b2v += bf16_lo(ub.y); b3  += bf16_hi(ub.y);           \
    b4v += bf16_lo(ub.z); b5  += bf16_hi(ub.z);           \
    b6  += bf16_lo(ub.w); b7  += bf16_hi(ub.w);

// ---------- aggregation: 2-node waves + quad-round loads (MLP>=8) ----------
// R11 (paired loads, MLP>=4) gave -1.7us. Extend: issue all EIGHT row-loads
// of 4 consecutive rounds before any accumulation; remainder handles
// rounds%4==2 (rounds is always even). Accumulation order per node is
// UNCHANGED (rounds j, j+1, j+2, j+3 in sequence) -> bit-identical output.
__global__ __launch_bounds__(256) void aggregate(const unsigned* __restrict__ Zb,
                                                 const int* __restrict__ nodeStart,
                                                 const int* __restrict__ nodeEnd,
                                                 const unsigned short* __restrict__ csr16,
                                                 const float* __restrict__ dinv,
                                                 const float* __restrict__ bias,
                                                 float* __restrict__ Out, int N,
                                                 const float* __restrict__ W2,
                                                 unsigned* __restrict__ Zout) {
    __shared__ float rowsLds[8][128];    // 4 KB (used only in fused mode)
    const bool fused = (W2 != nullptr);
    int wv    = __builtin_amdgcn_readfirstlane(threadIdx.x >> 6);
    int nodeA = blockIdx.x * 8 + wv * 2;
    bool active = (nodeA < N);
    if (!fused && !active) return;
    int lane = threadIdx.x & 63;
    int l16  = lane & 15;       // uint4 slot within 256 B row

    if (active) {
        int nodeB = nodeA + 1;
        bool hasB = (nodeB < N);
        int g = lane >> 4;      // 0..3 edge sub-group

        const uint4* Z4 = (const uint4*)Zb;     // row = 16 uint4
        float a0=0.f,a1=0.f,a2=0.f,a3=0.f,a4=0.f,a5=0.f,a6=0.f,a7=0.f;
        float b0=0.f,b1v=0.f,b2v=0.f,b3=0.f,b4v=0.f,b5=0.f,b6=0.f,b7=0.f;

        int eA = nodeStart[nodeA], endA = nodeEnd[nodeA];
        int eB = 0, endB = 0;
        if (hasB) { eB = nodeStart[nodeB]; endB = nodeEnd[nodeB]; }

        while (eA < endA || eB < endB) {
            int remA = endA - eA; int cntA = remA > 64 ? 64 : (remA > 0 ? remA : 0);
            int remB = endB - eB; int cntB = remB > 64 ? 64 : (remB > 0 ? remB : 0);
            int myA = (lane < cntA) ? (int)csr16[eA + lane] : N;   // sentinel pad
            int myB = (lane < cntB) ? (int)csr16[eB + lane] : N;
            int cmax = cntA > cntB ? cntA : cntB;
            int rounds = cmax >> 2;             // always even (cnts multiple of 8)
            int j = 0;
            #pragma unroll 4
            for (; j + 4 <= rounds; j += 4) {
                int iA0 = __shfl(myA, j * 4 +      g);
                int iB0 = __shfl(myB, j * 4 +      g);
                int iA1 = __shfl(myA, j * 4 +  4 + g);
                int iB1 = __shfl(myB, j * 4 +  4 + g);
                int iA2 = __shfl(myA, j * 4 +  8 + g);
                int iB2 = __shfl(myB, j * 4 +  8 + g);
                int iA3 = __shfl(myA, j * 4 + 12 + g);
                int iB3 = __shfl(myB, j * 4 + 12 + g);
                uint4 ua0 = Z4[iA0 * 16 + l16];
                uint4 ub0 = Z4[iB0 * 16 + l16];
                uint4 ua1 = Z4[iA1 * 16 + l16];
                uint4 ub1 = Z4[iB1 * 16 + l16];
                uint4 ua2 = Z4[iA2 * 16 + l16];
                uint4 ub2 = Z4[iB2 * 16 + l16];
                uint4 ua3 = Z4[iA3 * 16 + l16];
                uint4 ub3 = Z4[iB3 * 16 + l16];
                ACC_AB(ua0, ub0)
                ACC_AB(ua1, ub1)
                ACC_AB(ua2, ub2)
                ACC_AB(ua3, ub3)
            }
            if (j < rounds) {                   // remainder: exactly 2 rounds
                int iA0 = __shfl(myA, j * 4 +     g);
                int iB0 = __shfl(myB, j * 4 +     g);
                int iA1 = __shfl(myA, j * 4 + 4 + g);
                int iB1 = __shfl(myB, j * 4 + 4 + g);
                uint4 ua0 = Z4[iA0 * 16 + l16];
                uint4 ub0 = Z4[iB0 * 16 + l16];
                uint4 ua1 = Z4[iA1 * 16 + l16];
                uint4 ub1 = Z4[iB1 * 16 + l16];
                ACC_AB(ua0, ub0)
                ACC_AB(ua1, ub1)
            }
            eA += cntA; eB += cntB;
        }
        // reduce across the 4 edge-groups (lane bits 4..5)
        #pragma unroll
        for (int m = 16; m <= 32; m <<= 1) {
            a0 += __shfl_xor(a0, m); a1 += __shfl_xor(a1, m);
            a2 += __shfl_xor(a2, m); a3 += __shfl_xor(a3, m);
            a4 += __shfl_xor(a4, m); a5 += __shfl_xor(a5, m);
            a6 += __shfl_xor(a6, m); a7 += __shfl_xor(a7, m);
            b0  += __shfl_xor(b0, m);  b1v += __shfl_xor(b1v, m);
            b2v += __shfl_xor(b2v, m); b3  += __shfl_xor(b3, m);
            b4v += __shfl_xor(b4v, m); b5  += __shfl_xor(b5, m);
            b6  += __shfl_xor(b6, m);  b7  += __shfl_xor(b7, m);
        }
        // lanes 0-15 -> node A; lanes 16-31 -> node B
        int half = lane >> 4;
        if (half == 0 || (half == 1 && hasB)) {
            int node = half ? nodeB : nodeA;
            float r0 = half ? b0  : a0, r1 = half ? b1v : a1;
            float r2 = half ? b2v : a2, r3 = half ? b3  : a3;
            float r4 = half ? b4v : a4, r5 = half ? b5  : a5;
            float r6 = half ? b6  : a6, r7 = half ? b7  : a7;
            uint4 su = Z4[node * 16 + l16];
            float dv = dinv[node];
            const float4* bp4 = (const float4*)bias;
            float4 ba = bp4[l16 * 2], bb = bp4[l16 * 2 + 1];
            float4 o0, o1;
            o0.x = (r0 + bf16_lo(su.x)) * dv + ba.x;
            o0.y = (r1 + bf16_hi(su.x)) * dv + ba.y;
            o0.z = (r2 + bf16_lo(su.y)) * dv + ba.z;
            o0.w = (r3 + bf16_hi(su.y)) * dv + ba.w;
            o1.x = (r4 + bf16_lo(su.z)) * dv + bb.x;
            o1.y = (r5 + bf16_hi(su.z)) * dv + bb.y;
            o1.z = (r6 + bf16_lo(su.w)) * dv + bb.z;
            o1.w = (r7 + bf16_hi(su.w)) * dv + bb.w;
            if (fused) {
                float4* rp = (float4*)&rowsLds[wv * 2 + half][0];
                rp[l16 * 2]     = o0;
                rp[l16 * 2 + 1] = o1;
            } else {
                float4* op = (float4*)Out + (size_t)node * 32 + l16 * 2;
                op[0] = o0;
                op[1] = o1;
            }
        }
    }

    if (fused) {
        __syncthreads();
        int tid  = threadIdx.x;
        int colg = (tid & 31) << 2;          // 4 consecutive cols
        int r    = tid >> 5;                 // 0..7
        int node = blockIdx.x * 8 + r;
        const float* xrow = &rowsLds[r][0];
        float ac0 = 0.f, ac1 = 0.f, ac2 = 0.f, ac3 = 0.f;
        #pragma unroll 8
        for (int k = 0; k < 128; ++k) {      // ascending k == reference order
            float xs = xrow[k];
            float4 w4 = *(const float4*)(W2 + (size_t)k * D + colg);
            ac0 = fmaf(xs, w4.x, ac0);
            ac1 = fmaf(xs, w4.y, ac1);
            ac2 = fmaf(xs, w4.z, ac2);
            ac3 = fmaf(xs, w4.w, ac3);
        }
        if (node < N) {
            float dv = dinv[node];
            uint2 o;
            o.x = (rne_bf16(ac1 * dv) << 16) | rne_bf16(ac0 * dv);
            o.y = (rne_bf16(ac3 * dv) << 16) | rne_bf16(ac2 * dv);
            ((uint2*)Zout)[(size_t)node * 32 + (colg >> 2)] = o;
        }
    }
}

extern "C" void kernel_launch(void* const* d_in, const int* in_sizes, int n_in,
                              void* d_out, int out_size, void* d_ws, size_t ws_size,
                              hipStream_t stream) {
    const float* X  = (const float*)d_in[0];
    const int*   ed = (const int*)d_in[1];
    const float* W1 = (const float*)d_in[2];
    const float* b1 = (const float*)d_in[3];
    const float* W2 = (const float*)d_in[4];
    const float* b2 = (const float*)d_in[5];
    float* out = (float*)d_out;

    const int N = in_sizes[0] / D;       // 10000
    const int E = in_sizes[1] / 2;       // 640000
    const int* src = ed;
    const int* dst = ed + E;

    char* w = (char*)d_ws;
    float*    Y        = (float*)w;            w += (size_t)N * D * sizeof(float);
    unsigned* Zb       = (unsigned*)w;         w += (size_t)(N + 1) * 64 * sizeof(unsigned);
    unsigned* Zb2      = (unsigned*)w;         w += (size_t)(N + 1) * 64 * sizeof(unsigned);
    int*      binned   = (int*)w;              w += (size_t)NBINS * SLABW * sizeof(int);
    unsigned short* csr16 = (unsigned short*)w; w += (size_t)NBINS * BIN_CAP * sizeof(unsigned short);
    float*    dinv     = (float*)w;            w += (size_t)N * sizeof(float);
    int*      nodeStart= (int*)w;              w += (size_t)N * sizeof(int);
    int*      nodeEnd  = (int*)w;              w += (size_t)N * sizeof(int);
    int*      cntMat   = (int*)w;              w += (size_t)NBINS * NBINS * sizeof(int);

    int gGemm1 = (N + 31) / 32;                 // 313
    int gScat  = (E + EPB - 1) / EPB;           // 157
    fused_gemm_scatter<<<gGemm1 + gScat, 512, 0, stream>>>(
        X, W1, Y, src, dst, cntMat, binned, E, N, gGemm1);
    sort_bins<<<NBINS, 1024, 0, stream>>>(cntMat, binned, csr16, dinv,
                                          nodeStart, nodeEnd, Y, Zb, Zb2, N);

    int gAgg = (N + 7) / 8;                     // 1250: two nodes per wave
    // layer 1: aggregate + fused layer-2 linear -> Zb2 (bf16, scaled)
    aggregate<<<gAgg, 256, 0, stream>>>(Zb, nodeStart, nodeEnd, csr16, dinv,
                                        b1, out, N, W2, Zb2);
    // layer 2: aggregate -> final output
    aggregate<<<gAgg, 256, 0, stream>>>(Zb2, nodeStart, nodeEnd, csr16, dinv,
                                        b2, out, N, nullptr, nullptr);
}